// Round 10
// baseline (97.002 us; speedup 1.0000x reference)
//
#include <hip/hip_runtime.h>
#include <hip/hip_bf16.h>
#include <math.h>

// HGCN decoder, B=512, N=128, D=256, F=16, L=3, c=1 Poincare ball.
// LDS-read-throughput-bound analysis (R6-R9): cut ds_read_b128 count via
// 32x32x16 MFMAs with ALL B-operands in registers.
//  - GEMM-a: wave owns (n-col of 32) x (m-half of 64): 32 A-reads/wave
//    (vs 64 in R6), B = Wt fragments in a 4+4 double-buffered register
//    pipeline (bfA/bfB, statically indexed, loads overlap MFMAs).
//  - GEMM-b: R9-verified 32x32 block (16 A-reads/wave, adj frags in regs).
// Block LDS reads/layer: 1536 (R6) -> 768. Padded-linear LDS, cvt_pkrtz
// packing, f16x4 stores. 16 waves/block, 1 block = 1 batch.

typedef _Float16 f16;
typedef f16 f16x8 __attribute__((ext_vector_type(8)));
typedef f16 f16x4 __attribute__((ext_vector_type(4)));
typedef f16 f16x2 __attribute__((ext_vector_type(2)));
typedef __fp16 fp16x2_cv __attribute__((ext_vector_type(2)));
typedef float f32x4 __attribute__((ext_vector_type(4)));
typedef float f32x16 __attribute__((ext_vector_type(16)));

#define NB 512
#define NN 128
#define ND 256
#define NF 16
#define NL 3

#define SDT 264   // sT row stride f16: 528B = 132 words, %32 = 4
#define SDV 136   // sV row stride f16: 272B =  68 words, %32 = 4

#define EPSV   1e-7f
#define MAXN   0.99999f      // 1 - 1e-5
#define ATHMAX 6.1030340f    // atanh(1 - 1e-5)

__device__ __forceinline__ f16x4 pack4(float a, float b, float c, float d) {
    fp16x2_cv lo = __builtin_amdgcn_cvt_pkrtz(a, b);
    fp16x2_cv hi = __builtin_amdgcn_cvt_pkrtz(c, d);
    f16x2 lo2, hi2;
    __builtin_memcpy(&lo2, &lo, sizeof(lo2));
    __builtin_memcpy(&hi2, &hi, sizeof(hi2));
    return __builtin_shufflevector(lo2, hi2, 0, 1, 2, 3);
}

// One-time: Wt[l][n][k] = W[l][k][n] (f16), WoutT[f][k] = Wout[k][f] (f16).
__global__ void prep_kernel(const float* __restrict__ Ws,
                            const float* __restrict__ Wout,
                            f16* __restrict__ Wt, f16* __restrict__ WoutT) {
    int idx = blockIdx.x * 256 + threadIdx.x;
    if (idx < NL * ND * ND) {
        int l = idx / (ND * ND);
        int r = idx % (ND * ND);
        int n = r >> 8;
        int k = r & 255;
        Wt[idx] = (f16)Ws[l * ND * ND + k * ND + n];
    }
    if (idx < NF * ND) {
        int f = idx >> 8;
        int k = idx & 255;
        WoutT[idx] = (f16)Wout[k * NF + f];
    }
}

__global__ __launch_bounds__(1024, 4)
void hgcn_kernel(const float* __restrict__ x,
                 const float* __restrict__ adj,
                 const float* __restrict__ node_mask,
                 const f16*  __restrict__ Wt,
                 const float* __restrict__ bs,
                 const f16*  __restrict__ WoutT,
                 const float* __restrict__ bout,
                 float* __restrict__ out) {
    __shared__ __align__(16) f16 sT[NN * SDT];   // [node m][feat k] 66KB
    __shared__ __align__(16) f16 sV[ND * SDV];   // [feat n][node m] 68KB
    __shared__ __align__(16) float sRed[NN * 4]; // 4 partials per node 2KB

    const int b    = blockIdx.x;
    const int tid  = threadIdx.x;
    const int wave = tid >> 6;   // 0..15
    const int lane = tid & 63;
    const int l31  = lane & 31;
    const int hi   = lane >> 5;  // k-half for 32x32x16 fragments
    const int lg   = lane >> 4;  // 16x16 (head) only
    const int lc   = lane & 15;

    // GEMM-a roles (32x32): n-col nc (32 wide), m-half mh (2 tiles of 32).
    const int nc = wave & 7;     // 0..7
    const int mh = wave >> 3;    // 0..1
    // GEMM-b roles (32x32): i-col ic, n-tile pair {2*nr2, 2*nr2+1}.
    const int nr2 = wave >> 2;   // 0..3
    const int ic  = wave & 3;    // 0..3

    const f32x16 fzero16 = {0.f};

    // ---------- adj B-fragments (32 VGPR, reused all 3 layers) -------------
    // GEMM-b: U^T[n][i] = sum_j V^T[n][j]*adj[i][j]; B[k=j][col=i] =
    // adj[ic*32+l31][j], j = ks*16 + hi*8 .. +7.   (R9-verified)
    f16x8 adjf[8];
    {
        const float* adjb = adj + (size_t)b * NN * NN;
        #pragma unroll
        for (int ks = 0; ks < 8; ++ks) {
            const float4* ap = (const float4*)(adjb + (ic * 32 + l31) * NN + ks * 16 + hi * 8);
            float4 alo = ap[0], ahi = ap[1];
            f16x4 l4 = pack4(alo.x, alo.y, alo.z, alo.w);
            f16x4 h4 = pack4(ahi.x, ahi.y, ahi.z, ahi.w);
            adjf[ks] = __builtin_shufflevector(l4, h4, 0, 1, 2, 3, 4, 5, 6, 7);
        }
    }

    // ---------- GEMM-a B-register pipeline: quarter 0 of layer 0 ----------
    // B-frag (32x32x16): lane l31 = col n = nc*32+l31, hi = k-half,
    // 8 f16 contiguous in k from Wt[n][k].
    const f16* wrow = Wt + (nc * 32 + l31) * ND + hi * 8;
    f16x8 bfA[4], bfB[4];
    #pragma unroll
    for (int k = 0; k < 4; ++k)
        bfA[k] = *(const f16x8*)(wrow + k * 16);

    // ---------- init: sT = f16(logmap0(proj(x[b]))), 8 rows per wave -------
    {
        const float4* xb = (const float4*)(x + (size_t)b * NN * ND);
        #pragma unroll
        for (int r = 0; r < 8; ++r) {
            int row = wave * 8 + r;
            float4 v = xb[row * 64 + lane];
            float ssq = v.x * v.x + v.y * v.y + v.z * v.z + v.w * v.w;
            #pragma unroll
            for (int d = 1; d < 64; d <<= 1) ssq += __shfl_xor(ssq, d);
            float norm = sqrtf(ssq);
            float sc1 = (norm > MAXN) ? (MAXN / norm) : 1.0f;      // proj
            float hn  = fmaxf(norm * sc1, EPSV);
            float aa  = fminf(hn, MAXN);
            float ath = 0.5f * __logf((1.0f + aa) / (1.0f - aa));  // atanh
            float s   = sc1 * ath / hn;                            // logmap0
            *(f16x4*)&sT[row * SDT + lane * 4] =
                pack4(v.x * s, v.y * s, v.z * s, v.w * s);
        }
    }
    __syncthreads();

    for (int layer = 0; layer < NL; ++layer) {
        const f16* wrowL = wrow + layer * ND * ND;
        const int m0 = mh * 64;

        // ---- GEMM-a: V[m][n] = T @ W + b (32x32x16), 2 m-tiles x 1 n-col.
        // A = sT rows (LDS, 32 reads); B = register pipeline (bfA/bfB,
        // 4-frag quarters: load q+1 while MFMA-ing q).
        f32x16 acc_a0 = fzero16, acc_a1 = fzero16;

        // q0 (bfA) | load q1 -> bfB
        #pragma unroll
        for (int k = 0; k < 4; ++k)
            bfB[k] = *(const f16x8*)(wrowL + (4 + k) * 16);
        #pragma unroll
        for (int ksl = 0; ksl < 4; ++ksl) {
            f16x8 a0 = *(const f16x8*)&sT[(m0 +      l31) * SDT + ksl * 16 + hi * 8];
            f16x8 a1 = *(const f16x8*)&sT[(m0 + 32 + l31) * SDT + ksl * 16 + hi * 8];
            acc_a0 = __builtin_amdgcn_mfma_f32_32x32x16_f16(a0, bfA[ksl], acc_a0, 0, 0, 0);
            acc_a1 = __builtin_amdgcn_mfma_f32_32x32x16_f16(a1, bfA[ksl], acc_a1, 0, 0, 0);
        }
        // q1 (bfB) | load q2 -> bfA
        #pragma unroll
        for (int k = 0; k < 4; ++k)
            bfA[k] = *(const f16x8*)(wrowL + (8 + k) * 16);
        #pragma unroll
        for (int ksl = 0; ksl < 4; ++ksl) {
            f16x8 a0 = *(const f16x8*)&sT[(m0 +      l31) * SDT + 64 + ksl * 16 + hi * 8];
            f16x8 a1 = *(const f16x8*)&sT[(m0 + 32 + l31) * SDT + 64 + ksl * 16 + hi * 8];
            acc_a0 = __builtin_amdgcn_mfma_f32_32x32x16_f16(a0, bfB[ksl], acc_a0, 0, 0, 0);
            acc_a1 = __builtin_amdgcn_mfma_f32_32x32x16_f16(a1, bfB[ksl], acc_a1, 0, 0, 0);
        }
        // q2 (bfA) | load q3 -> bfB
        #pragma unroll
        for (int k = 0; k < 4; ++k)
            bfB[k] = *(const f16x8*)(wrowL + (12 + k) * 16);
        #pragma unroll
        for (int ksl = 0; ksl < 4; ++ksl) {
            f16x8 a0 = *(const f16x8*)&sT[(m0 +      l31) * SDT + 128 + ksl * 16 + hi * 8];
            f16x8 a1 = *(const f16x8*)&sT[(m0 + 32 + l31) * SDT + 128 + ksl * 16 + hi * 8];
            acc_a0 = __builtin_amdgcn_mfma_f32_32x32x16_f16(a0, bfA[ksl], acc_a0, 0, 0, 0);
            acc_a1 = __builtin_amdgcn_mfma_f32_32x32x16_f16(a1, bfA[ksl], acc_a1, 0, 0, 0);
        }
        // q3 (bfB) | prefetch next layer's q0 -> bfA (bfA dead after q2)
        if (layer + 1 < NL) {
            const f16* wn = wrowL + ND * ND;
            #pragma unroll
            for (int k = 0; k < 4; ++k)
                bfA[k] = *(const f16x8*)(wn + k * 16);
        }
        #pragma unroll
        for (int ksl = 0; ksl < 4; ++ksl) {
            f16x8 a0 = *(const f16x8*)&sT[(m0 +      l31) * SDT + 192 + ksl * 16 + hi * 8];
            f16x8 a1 = *(const f16x8*)&sT[(m0 + 32 + l31) * SDT + 192 + ksl * 16 + hi * 8];
            acc_a0 = __builtin_amdgcn_mfma_f32_32x32x16_f16(a0, bfB[ksl], acc_a0, 0, 0, 0);
            acc_a1 = __builtin_amdgcn_mfma_f32_32x32x16_f16(a1, bfB[ksl], acc_a1, 0, 0, 0);
        }

        // epilogue-a (R7-verified): +bias, pack f16x4, store sV[n][m].
        {
            int n = nc * 32 + l31;
            float bias = bs[layer * ND + n];
            #pragma unroll
            for (int g = 0; g < 4; ++g) {
                int ma = m0 + 8 * g + 4 * hi;
                *(f16x4*)&sV[n * SDV + ma] =
                    pack4(acc_a0[4 * g + 0] + bias, acc_a0[4 * g + 1] + bias,
                          acc_a0[4 * g + 2] + bias, acc_a0[4 * g + 3] + bias);
                *(f16x4*)&sV[n * SDV + ma + 32] =
                    pack4(acc_a1[4 * g + 0] + bias, acc_a1[4 * g + 1] + bias,
                          acc_a1[4 * g + 2] + bias, acc_a1[4 * g + 3] + bias);
            }
        }
        __syncthreads();

        // ---- GEMM-b: U^T[n][i] (32x32x16), R9-verified. 2 n-tiles x i-col.
        f32x16 acc_b0 = fzero16, acc_b1 = fzero16;
        #pragma unroll
        for (int ks = 0; ks < 8; ++ks) {
            f16x8 a0 = *(const f16x8*)&sV[((2 * nr2 + 0) * 32 + l31) * SDV + ks * 16 + hi * 8];
            f16x8 a1 = *(const f16x8*)&sV[((2 * nr2 + 1) * 32 + l31) * SDV + ks * 16 + hi * 8];
            acc_b0 = __builtin_amdgcn_mfma_f32_32x32x16_f16(a0, adjf[ks], acc_b0, 0, 0, 0);
            acc_b1 = __builtin_amdgcn_mfma_f32_32x32x16_f16(a1, adjf[ks], acc_b1, 0, 0, 0);
        }

        // ---- epilogue-b (R9-verified): relu + node-norm partials.
        float ssq = 0.f;
        #pragma unroll
        for (int r = 0; r < 16; ++r) {
            float v0 = fmaxf(acc_b0[r], 0.0f);
            float v1 = fmaxf(acc_b1[r], 0.0f);
            acc_b0[r] = v0;
            acc_b1[r] = v1;
            ssq += v0 * v0 + v1 * v1;
        }
        ssq += __shfl_xor(ssq, 32);   // fold the two row-halves (same col i)
        if (lane < 32) sRed[(ic * 32 + l31) * 4 + nr2] = ssq;
        __syncthreads();

        f32x4 p = *(const f32x4*)&sRed[(ic * 32 + l31) * 4];
        float tot = p[0] + p[1] + p[2] + p[3];
        float nu = sqrtf(tot);
        float scale = (nu > ATHMAX) ? (ATHMAX / nu) : 1.0f;

        // fused logmap0(proj(expmap0(u))) = u * min(1, ATHMAX/||u||) -> sT.
        {
            int i = ic * 32 + l31;
            #pragma unroll
            for (int g = 0; g < 4; ++g) {
                int n0 = (2 * nr2 + 0) * 32 + 8 * g + 4 * hi;
                int n1 = (2 * nr2 + 1) * 32 + 8 * g + 4 * hi;
                *(f16x4*)&sT[i * SDT + n0] =
                    pack4(acc_b0[4 * g + 0] * scale, acc_b0[4 * g + 1] * scale,
                          acc_b0[4 * g + 2] * scale, acc_b0[4 * g + 3] * scale);
                *(f16x4*)&sT[i * SDT + n1] =
                    pack4(acc_b1[4 * g + 0] * scale, acc_b1[4 * g + 1] * scale,
                          acc_b1[4 * g + 2] * scale, acc_b1[4 * g + 3] * scale);
            }
        }
        __syncthreads();
    }

    // ---------- head: out = (out_tan @ Wout + bout) * node_mask ------------
    if (wave < 8) {
        f32x4 acc = {0.f, 0.f, 0.f, 0.f};
        #pragma unroll
        for (int ks = 0; ks < 8; ++ks) {
            f16x8 afr = *(const f16x8*)&sT[(wave * 16 + lc) * SDT + ks * 32 + lg * 8];
            f16x8 bfr = *(const f16x8*)(WoutT + lc * ND + ks * 32 + lg * 8);
            acc = __builtin_amdgcn_mfma_f32_16x16x32_f16(afr, bfr, acc, 0, 0, 0);
        }
        #pragma unroll
        for (int r = 0; r < 4; ++r) {
            int row = wave * 16 + lg * 4 + r;
            float mask = node_mask[b * NN + row];
            out[((size_t)b * NN + row) * NF + lc] = (acc[r] + bout[lc]) * mask;
        }
    }
}

extern "C" void kernel_launch(void* const* d_in, const int* in_sizes, int n_in,
                              void* d_out, int out_size, void* d_ws, size_t ws_size,
                              hipStream_t stream) {
    const float* x    = (const float*)d_in[0];
    const float* adj  = (const float*)d_in[1];
    const float* mask = (const float*)d_in[2];
    const float* Ws   = (const float*)d_in[3];
    const float* bsp  = (const float*)d_in[4];
    const float* Wout = (const float*)d_in[5];
    const float* bout = (const float*)d_in[6];

    f16* Wt    = (f16*)d_ws;                       // 3*256*256 f16 = 384KB
    f16* WoutT = Wt + NL * ND * ND;                // 16*256 f16 = 8KB

    prep_kernel<<<768, 256, 0, stream>>>(Ws, Wout, Wt, WoutT);
    hgcn_kernel<<<NB, 1024, 0, stream>>>(x, adj, mask, Wt, bsp, WoutT, bout,
                                         (float*)d_out);
}